// Round 1
// baseline (928.731 us; speedup 1.0000x reference)
//
#include <hip/hip_runtime.h>

#define NN 100000
#define NE 1600000
#define NG 512
#define HID 128
#define FPD 2048

// ---------------- CSR build ----------------

__global__ __launch_bounds__(256) void hist_kernel(const int* __restrict__ dst,
                                                   int* __restrict__ cnt, int E) {
  int i = blockIdx.x * 256 + threadIdx.x;
  if (i < E) atomicAdd(&cnt[dst[i]], 1);
}

// per-block inclusive scan of 1024 ints (4/thread), writes scanned chunk + block sum
__global__ __launch_bounds__(256) void scan1_kernel(const int* __restrict__ cnt,
                                                    int* __restrict__ partial,
                                                    int* __restrict__ bsums, int n) {
  __shared__ int lds[256];
  int t = threadIdx.x;
  int base = blockIdx.x * 1024 + t * 4;
  int4 v = make_int4(0, 0, 0, 0);
  if (base + 3 < n) {
    v = *reinterpret_cast<const int4*>(&cnt[base]);
  } else {
    if (base     < n) v.x = cnt[base];
    if (base + 1 < n) v.y = cnt[base + 1];
    if (base + 2 < n) v.z = cnt[base + 2];
    if (base + 3 < n) v.w = cnt[base + 3];
  }
  int s = v.x + v.y + v.z + v.w;
  lds[t] = s;
  __syncthreads();
  for (int off = 1; off < 256; off <<= 1) {
    int add = (t >= off) ? lds[t - off] : 0;
    __syncthreads();
    lds[t] += add;
    __syncthreads();
  }
  int run = lds[t] - s;  // exclusive offset of this thread within block
  run += v.x; if (base     < n) partial[base]     = run;
  run += v.y; if (base + 1 < n) partial[base + 1] = run;
  run += v.z; if (base + 2 < n) partial[base + 2] = run;
  run += v.w; if (base + 3 < n) partial[base + 3] = run;
  if (t == 255) bsums[blockIdx.x] = lds[255];
}

__global__ __launch_bounds__(256) void scan2_kernel(int* __restrict__ bsums, int nb) {
  __shared__ int lds[256];
  int t = threadIdx.x;
  int s = (t < nb) ? bsums[t] : 0;
  lds[t] = s;
  __syncthreads();
  for (int off = 1; off < 256; off <<= 1) {
    int add = (t >= off) ? lds[t - off] : 0;
    __syncthreads();
    lds[t] += add;
    __syncthreads();
  }
  if (t < nb) bsums[t] = lds[t] - s;  // exclusive block offsets, in-place
}

__global__ __launch_bounds__(256) void scan3_kernel(const int* __restrict__ partial,
                                                    const int* __restrict__ bsums,
                                                    int* __restrict__ rowptr, int n) {
  int i = blockIdx.x * 256 + threadIdx.x;
  if (i == 0) rowptr[0] = 0;
  if (i < n) rowptr[i + 1] = partial[i] + bsums[i >> 10];
}

__global__ __launch_bounds__(256) void scatter_kernel(const int* __restrict__ src,
                                                      const int* __restrict__ dst,
                                                      const int* __restrict__ rowptr,
                                                      int* __restrict__ cursor,
                                                      int* __restrict__ cols, int E) {
  int i = blockIdx.x * 256 + threadIdx.x;
  if (i < E) {
    int d = dst[i];
    int p = atomicAdd(&cursor[d], 1);
    cols[rowptr[d] + p] = src[i];
  }
}

// ---------------- aggregation: out[n,:] = sum_{e in CSR row n} H[cols[e],:] ----------------

__global__ __launch_bounds__(128) void agg_csr(const float* __restrict__ H,
                                               const int* __restrict__ rowptr,
                                               const int* __restrict__ cols,
                                               float* __restrict__ out) {
  int n = blockIdx.x;
  int t = threadIdx.x;
  int s = rowptr[n], e = rowptr[n + 1];
  float acc = 0.f;
  int i = s;
  for (; i + 1 < e; i += 2) {
    int c0 = cols[i];
    int c1 = cols[i + 1];
    acc += H[c0 * HID + t];
    acc += H[c1 * HID + t];
  }
  if (i < e) acc += H[cols[i] * HID + t];
  out[n * HID + t] = acc;
}

// ---------------- GEMM: C = prelu(A[rows,128] @ W[128,128] + bias + add, a) ----------------
// 256 threads, 32 rows/block, 4x4 micro-tile/thread, k-tiled LDS (20 KiB)

__global__ __launch_bounds__(256) void gemm128(const float* __restrict__ A,
                                               const float* __restrict__ W,
                                               const float* __restrict__ bias,
                                               const float* __restrict__ add,
                                               const float* __restrict__ pa,
                                               float* __restrict__ C, int rows) {
  __shared__ __align__(16) float Ws[32 * 128];  // Ws[k][j]
  __shared__ __align__(16) float As[32 * 32];   // As[k][r] (transposed tile)
  int t = threadIdx.x;
  int r0base = blockIdx.x * 32;
  int jt = (t & 31) * 4;   // 4 consecutive output cols
  int rt = (t >> 5) * 4;   // 4 consecutive output rows
  int rA = t & 31;         // staging: row
  int kg = t >> 5;         // staging: k-group (4 k's)
  float acc[4][4] = {{0.f}};

  for (int kt = 0; kt < 128; kt += 32) {
    // stage W tile [32][128]
#pragma unroll
    for (int i = 0; i < 16; ++i) {
      int idx = t + i * 256;
      int kk = idx >> 7, jj = idx & 127;
      Ws[idx] = W[(kt + kk) * 128 + jj];
    }
    // stage A^T tile: As[k][r]
    {
      int gr = r0base + rA;
      float4 av = make_float4(0.f, 0.f, 0.f, 0.f);
      if (gr < rows) av = *reinterpret_cast<const float4*>(&A[gr * 128 + kt + kg * 4]);
      const float* ap = reinterpret_cast<const float*>(&av);
#pragma unroll
      for (int i = 0; i < 4; ++i) As[(kg * 4 + i) * 32 + rA] = ap[i];
    }
    __syncthreads();
#pragma unroll
    for (int k = 0; k < 32; ++k) {
      float4 wv = *reinterpret_cast<const float4*>(&Ws[k * 128 + jt]);
      float4 av = *reinterpret_cast<const float4*>(&As[k * 32 + rt]);
      const float* wa = reinterpret_cast<const float*>(&wv);
      const float* aa = reinterpret_cast<const float*>(&av);
#pragma unroll
      for (int ri = 0; ri < 4; ++ri)
#pragma unroll
        for (int ci = 0; ci < 4; ++ci) acc[ri][ci] += aa[ri] * wa[ci];
    }
    __syncthreads();
  }

#pragma unroll
  for (int ri = 0; ri < 4; ++ri) {
    int r = r0base + rt + ri;
    if (r >= rows) continue;
    float4 v;
    float* vv = reinterpret_cast<float*>(&v);
#pragma unroll
    for (int ci = 0; ci < 4; ++ci) {
      float x = acc[ri][ci];
      if (bias) x += bias[jt + ci];
      if (add) x += add[r * 128 + jt + ci];
      if (pa) {
        float a = pa[jt + ci];
        x = x > 0.f ? x : a * x;
      }
      vv[ci] = x;
    }
    *reinterpret_cast<float4*>(&C[r * 128 + jt]) = v;
  }
}

// ---------------- mean pool over sorted batch ----------------

__device__ __forceinline__ int lower_bound_dev(const int* __restrict__ arr, int n, int val) {
  int lo = 0, hi = n;
  while (lo < hi) {
    int mid = (lo + hi) >> 1;
    if (arr[mid] < val) lo = mid + 1; else hi = mid;
  }
  return lo;
}

__global__ __launch_bounds__(128) void pool_mean(const float* __restrict__ H,
                                                 const int* __restrict__ batch,
                                                 float* __restrict__ pooled) {
  int g = blockIdx.x;
  int t = threadIdx.x;
  int start = lower_bound_dev(batch, NN, g);
  int end = lower_bound_dev(batch, NN, g + 1);
  float acc = 0.f;
  for (int r = start; r < end; ++r) acc += H[r * HID + t];
  int c = end - start;
  float inv = 1.f / (float)(c > 0 ? c : 1);
  pooled[g * HID + t] = acc * inv;
}

// ---------------- fingerprint head ----------------

__global__ __launch_bounds__(128) void fp_head(const float* __restrict__ fp,
                                               const float* __restrict__ Wfp,
                                               const float* __restrict__ bfp,
                                               const float* __restrict__ afp,
                                               float* __restrict__ femb) {
  __shared__ __align__(16) float fs[FPD];
  int g = blockIdx.x;
  int j = threadIdx.x;
  for (int i = j; i < FPD; i += 128) fs[i] = fp[g * FPD + i];
  __syncthreads();
  float acc = bfp[j];
  for (int k = 0; k < FPD; ++k) acc += fs[k] * Wfp[k * 128 + j];
  float a = afp[j];
  femb[g * 128 + j] = acc > 0.f ? acc : a * acc;
}

// ---------------- final: out[g] = [pooled|femb] . W_post + b ----------------

__global__ __launch_bounds__(64) void final_out(const float* __restrict__ pooled,
                                                const float* __restrict__ femb,
                                                const float* __restrict__ Wp,
                                                const float* __restrict__ bp,
                                                float* __restrict__ out) {
  int g = blockIdx.x;
  int t = threadIdx.x;
  float acc = 0.f;
  for (int i = t; i < 128; i += 64)
    acc += pooled[g * 128 + i] * Wp[i] + femb[g * 128 + i] * Wp[128 + i];
  for (int off = 32; off > 0; off >>= 1) acc += __shfl_down(acc, off);
  if (t == 0) out[g] = acc + bp[0];
}

// ---------------- launch ----------------

extern "C" void kernel_launch(void* const* d_in, const int* in_sizes, int n_in,
                              void* d_out, int out_size, void* d_ws, size_t ws_size,
                              hipStream_t stream) {
  const float* x      = (const float*)d_in[0];
  const float* fp     = (const float*)d_in[1];
  const int*   ei     = (const int*)d_in[2];
  const int*   batch  = (const int*)d_in[3];
  const float* W_pre  = (const float*)d_in[4];
  const float* b_pre  = (const float*)d_in[5];
  const float* a_pre  = (const float*)d_in[6];
  const float* Wl1    = (const float*)d_in[7];
  const float* bl1    = (const float*)d_in[8];
  const float* Wr1    = (const float*)d_in[9];
  const float* a1     = (const float*)d_in[10];
  const float* Wl2    = (const float*)d_in[11];
  const float* bl2    = (const float*)d_in[12];
  const float* Wr2    = (const float*)d_in[13];
  const float* a2     = (const float*)d_in[14];
  const float* W_fp   = (const float*)d_in[15];
  const float* b_fp   = (const float*)d_in[16];
  const float* a_fp   = (const float*)d_in[17];
  const float* W_post = (const float*)d_in[18];
  const float* b_post = (const float*)d_in[19];

  const int* src = ei;
  const int* dst = ei + NE;

  // workspace layout
  float* buf0 = (float*)d_ws;            // 12.8M floats
  float* buf1 = buf0 + (size_t)NN * HID;
  float* buf2 = buf1 + (size_t)NN * HID;
  int* cnt     = (int*)(buf2 + (size_t)NN * HID);  // NN
  int* rowptr  = cnt + NN;                          // NN+1
  int* bsums   = rowptr + NN + 2;                   // 128
  int* cursor  = bsums + 128;                       // NN
  int* partial = cursor + NN;                       // NN
  int* colsA   = partial + NN;                      // NE
  float* pooled = (float*)(colsA + NE);             // NG*HID
  float* femb   = pooled + NG * HID;                // NG*HID

  // --- build CSR (dst -> list of src) ---
  hipMemsetAsync(cnt, 0, NN * sizeof(int), stream);
  hist_kernel<<<(NE + 255) / 256, 256, 0, stream>>>(dst, cnt, NE);
  int nb = (NN + 1023) / 1024;  // 98
  scan1_kernel<<<nb, 256, 0, stream>>>(cnt, partial, bsums, NN);
  scan2_kernel<<<1, 256, 0, stream>>>(bsums, nb);
  scan3_kernel<<<(NN + 255) / 256, 256, 0, stream>>>(partial, bsums, rowptr, NN);
  hipMemsetAsync(cursor, 0, NN * sizeof(int), stream);
  scatter_kernel<<<(NE + 255) / 256, 256, 0, stream>>>(src, dst, rowptr, cursor, colsA, NE);

  int gGemm = (NN + 31) / 32;  // 3125

  // --- pre_mp: h0 = prelu(x @ W_pre + b_pre) -> buf0 ---
  gemm128<<<gGemm, 256, 0, stream>>>(x, W_pre, b_pre, nullptr, a_pre, buf0, NN);

  // --- conv1: h1 = prelu(agg(h0)@Wl1 + bl1 + h0@Wr1) ---
  agg_csr<<<NN, 128, 0, stream>>>(buf0, rowptr, colsA, buf1);
  gemm128<<<gGemm, 256, 0, stream>>>(buf0, Wr1, nullptr, nullptr, nullptr, buf2, NN);
  gemm128<<<gGemm, 256, 0, stream>>>(buf1, Wl1, bl1, buf2, a1, buf1, NN);  // in-place rows ok

  // --- conv2: h2 = prelu(agg(h1)@Wl2 + bl2 + h1@Wr2) ---
  agg_csr<<<NN, 128, 0, stream>>>(buf1, rowptr, colsA, buf0);
  gemm128<<<gGemm, 256, 0, stream>>>(buf1, Wr2, nullptr, nullptr, nullptr, buf2, NN);
  gemm128<<<gGemm, 256, 0, stream>>>(buf0, Wl2, bl2, buf2, a2, buf0, NN);  // h2 -> buf0

  // --- pool + heads ---
  pool_mean<<<NG, 128, 0, stream>>>(buf0, batch, pooled);
  fp_head<<<NG, 128, 0, stream>>>(fp, W_fp, b_fp, a_fp, femb);
  final_out<<<NG, 64, 0, stream>>>(pooled, femb, W_post, b_post, (float*)d_out);
}

// Round 3
// 762.895 us; speedup vs baseline: 1.2174x; 1.2174x over previous
//
#include <hip/hip_runtime.h>

#define NN 100000
#define NE 1600000
#define NG 512
#define HID 128
#define FPD 2048

typedef __attribute__((ext_vector_type(8))) short bf16x8;
typedef __attribute__((ext_vector_type(4))) float f32x4;

static __device__ __forceinline__ ushort f2bf(float f) {
  union { float f; uint u; } v; v.f = f;
  uint u = v.u;
  uint r = (u + 0x7fffu + ((u >> 16) & 1u)) >> 16;  // RNE
  return (ushort)r;
}
static __device__ __forceinline__ float bf2f(ushort h) {
  union { uint u; float f; } v; v.u = ((uint)h) << 16;
  return v.f;
}

// ---------------- CSR build ----------------

__global__ __launch_bounds__(256) void hist_kernel(const int* __restrict__ dst,
                                                   int* __restrict__ cnt, int E) {
  int i = blockIdx.x * 256 + threadIdx.x;
  if (i < E) atomicAdd(&cnt[dst[i]], 1);
}

__global__ __launch_bounds__(256) void scan1_kernel(const int* __restrict__ cnt,
                                                    int* __restrict__ partial,
                                                    int* __restrict__ bsums, int n) {
  __shared__ int lds[256];
  int t = threadIdx.x;
  int base = blockIdx.x * 1024 + t * 4;
  int4 v = make_int4(0, 0, 0, 0);
  if (base + 3 < n) {
    v = *reinterpret_cast<const int4*>(&cnt[base]);
  } else {
    if (base     < n) v.x = cnt[base];
    if (base + 1 < n) v.y = cnt[base + 1];
    if (base + 2 < n) v.z = cnt[base + 2];
    if (base + 3 < n) v.w = cnt[base + 3];
  }
  int s = v.x + v.y + v.z + v.w;
  lds[t] = s;
  __syncthreads();
  for (int off = 1; off < 256; off <<= 1) {
    int add = (t >= off) ? lds[t - off] : 0;
    __syncthreads();
    lds[t] += add;
    __syncthreads();
  }
  int run = lds[t] - s;
  run += v.x; if (base     < n) partial[base]     = run;
  run += v.y; if (base + 1 < n) partial[base + 1] = run;
  run += v.z; if (base + 2 < n) partial[base + 2] = run;
  run += v.w; if (base + 3 < n) partial[base + 3] = run;
  if (t == 255) bsums[blockIdx.x] = lds[255];
}

__global__ __launch_bounds__(256) void scan2_kernel(int* __restrict__ bsums, int nb) {
  __shared__ int lds[256];
  int t = threadIdx.x;
  int s = (t < nb) ? bsums[t] : 0;
  lds[t] = s;
  __syncthreads();
  for (int off = 1; off < 256; off <<= 1) {
    int add = (t >= off) ? lds[t - off] : 0;
    __syncthreads();
    lds[t] += add;
    __syncthreads();
  }
  if (t < nb) bsums[t] = lds[t] - s;
}

__global__ __launch_bounds__(256) void scan3_kernel(const int* __restrict__ partial,
                                                    const int* __restrict__ bsums,
                                                    int* __restrict__ rowptr, int n) {
  int i = blockIdx.x * 256 + threadIdx.x;
  if (i == 0) rowptr[0] = 0;
  if (i < n) rowptr[i + 1] = partial[i] + bsums[i >> 10];
}

__global__ __launch_bounds__(256) void scatter_kernel(const int* __restrict__ src,
                                                      const int* __restrict__ dst,
                                                      const int* __restrict__ rowptr,
                                                      int* __restrict__ cursor,
                                                      int* __restrict__ cols, int E) {
  int i = blockIdx.x * 256 + threadIdx.x;
  if (i < E) {
    int d = dst[i];
    int p = atomicAdd(&cursor[d], 1);
    cols[rowptr[d] + p] = src[i];
  }
}

// ---------------- conversions ----------------

// x -> hi/lo bf16 split
__global__ __launch_bounds__(256) void cvt_x_split(const float* __restrict__ x,
                                                   ushort* __restrict__ xh,
                                                   ushort* __restrict__ xl, int n4) {
  int i = blockIdx.x * 256 + threadIdx.x;
  if (i < n4) {
    float4 v = *reinterpret_cast<const float4*>(&x[i * 4]);
    ushort4 h, l;
    h.x = f2bf(v.x); l.x = f2bf(v.x - bf2f(h.x));
    h.y = f2bf(v.y); l.y = f2bf(v.y - bf2f(h.y));
    h.z = f2bf(v.z); l.z = f2bf(v.z - bf2f(h.z));
    h.w = f2bf(v.w); l.w = f2bf(v.w - bf2f(h.w));
    *reinterpret_cast<ushort4*>(&xh[i * 4]) = h;
    *reinterpret_cast<ushort4*>(&xl[i * 4]) = l;
  }
}

// transpose + hi/lo split 5 [128][128] weights: Wt[w][j][k] = W[k][j]
__global__ __launch_bounds__(256) void cvt_w10(const float* __restrict__ w0,
                                               const float* __restrict__ w1,
                                               const float* __restrict__ w2,
                                               const float* __restrict__ w3,
                                               const float* __restrict__ w4,
                                               ushort* __restrict__ outh,
                                               ushort* __restrict__ outl) {
  int idx = blockIdx.x * 256 + threadIdx.x;  // 5*16384
  if (idx >= 5 * 16384) return;
  int w = idx >> 14, rem = idx & 16383;
  int j = rem >> 7, k = rem & 127;
  const float* W = (w == 0) ? w0 : (w == 1) ? w1 : (w == 2) ? w2 : (w == 3) ? w3 : w4;
  float v = W[k * 128 + j];
  ushort h = f2bf(v);
  outh[idx] = h;
  outl[idx] = f2bf(v - bf2f(h));
}

// ---------------- aggregation (bf16 in, hi/lo bf16 out) ----------------

__global__ __launch_bounds__(256) void agg_bf16(const ushort* __restrict__ H,
                                                const int* __restrict__ rowptr,
                                                const int* __restrict__ cols,
                                                ushort* __restrict__ outh,
                                                ushort* __restrict__ outl) {
  int node = blockIdx.x * 4 + (threadIdx.x >> 6);
  int lane = threadIdx.x & 63;
  int s = rowptr[node], e = rowptr[node + 1];
  float a0 = 0.f, a1 = 0.f;
  int i = s;
  for (; i + 3 < e; i += 4) {
    int c0 = cols[i], c1 = cols[i + 1], c2 = cols[i + 2], c3 = cols[i + 3];
    uint u0 = *reinterpret_cast<const uint*>(&H[(size_t)c0 * 128 + lane * 2]);
    uint u1 = *reinterpret_cast<const uint*>(&H[(size_t)c1 * 128 + lane * 2]);
    uint u2 = *reinterpret_cast<const uint*>(&H[(size_t)c2 * 128 + lane * 2]);
    uint u3 = *reinterpret_cast<const uint*>(&H[(size_t)c3 * 128 + lane * 2]);
    a0 += bf2f((ushort)(u0 & 0xffff)) + bf2f((ushort)(u1 & 0xffff)) +
          bf2f((ushort)(u2 & 0xffff)) + bf2f((ushort)(u3 & 0xffff));
    a1 += bf2f((ushort)(u0 >> 16)) + bf2f((ushort)(u1 >> 16)) +
          bf2f((ushort)(u2 >> 16)) + bf2f((ushort)(u3 >> 16));
  }
  for (; i < e; ++i) {
    uint u0 = *reinterpret_cast<const uint*>(&H[(size_t)cols[i] * 128 + lane * 2]);
    a0 += bf2f((ushort)(u0 & 0xffff));
    a1 += bf2f((ushort)(u0 >> 16));
  }
  ushort h0 = f2bf(a0), h1 = f2bf(a1);
  ushort l0 = f2bf(a0 - bf2f(h0)), l1 = f2bf(a1 - bf2f(h1));
  *reinterpret_cast<uint*>(&outh[(size_t)node * 128 + lane * 2]) = (uint)h0 | ((uint)h1 << 16);
  *reinterpret_cast<uint*>(&outl[(size_t)node * 128 + lane * 2]) = (uint)l0 | ((uint)l1 << 16);
}

// ---------------- MFMA GEMM with hi/lo error compensation ----------------
// MODE 0: C = prelu(A1@W1 + bias)            terms: A1h@W1h + A1h@W1l + A1l@W1h   (bf16 out)
// MODE 1: C = prelu(A1@W1 + A2@W2 + bias)    terms: +A2@W2h + A2@W2l              (bf16 out)
// MODE 2: same as 1, fp32 out
// 256 thr = 4 waves; tile 64 rows x 128 cols; A tiles in LDS w/ XOR swizzle.

template <int MODE>
__global__ __launch_bounds__(256) void gemm_mfma(const ushort* __restrict__ A1h,
                                                 const ushort* __restrict__ A1l,
                                                 const ushort* __restrict__ A2,
                                                 const ushort* __restrict__ W1h,
                                                 const ushort* __restrict__ W1l,
                                                 const ushort* __restrict__ W2h,
                                                 const ushort* __restrict__ W2l,
                                                 const float* __restrict__ bias,
                                                 const float* __restrict__ pa,
                                                 ushort* __restrict__ Cb,
                                                 float* __restrict__ Cf, int rows) {
  constexpr int NT = (MODE == 0) ? 2 : 3;
  __shared__ __align__(16) ushort lds[NT * 64 * 128];
  char* ldsb = (char*)lds;
  int t = threadIdx.x;
  int r0 = blockIdx.x * 64;

  int sr = t >> 2, sc = t & 3;
  int grow = r0 + sr;
  if (grow > rows - 1) grow = rows - 1;
  const ushort* srcs[3];
  srcs[0] = &A1h[(size_t)grow * 128 + sc * 32];
  srcs[1] = &A1l[(size_t)grow * 128 + sc * 32];
  if (NT == 3) srcs[2] = &A2[(size_t)grow * 128 + sc * 32];
#pragma unroll
  for (int m = 0; m < NT; ++m) {
#pragma unroll
    for (int u = 0; u < 4; ++u) {
      int q = sr * 256 + sc * 64 + u * 16;
      int a = q ^ ((sr & 7) << 4);
      *reinterpret_cast<bf16x8*>(ldsb + m * 16384 + a) =
          *reinterpret_cast<const bf16x8*>(srcs[m] + u * 8);
    }
  }
  __syncthreads();

  int wave = t >> 6, lane = t & 63;
  int lrow = lane & 15, lk = lane >> 4;
  int arow = (wave << 4) + lrow;
  int aswz = (arow & 7) << 4;

  const bf16x8* Wv1h = reinterpret_cast<const bf16x8*>(W1h);
  const bf16x8* Wv1l = reinterpret_cast<const bf16x8*>(W1l);
  const bf16x8* Wv2h = reinterpret_cast<const bf16x8*>(W2h);
  const bf16x8* Wv2l = reinterpret_cast<const bf16x8*>(W2l);

  f32x4 acc[8];
#pragma unroll
  for (int n = 0; n < 8; ++n) acc[n] = (f32x4){0.f, 0.f, 0.f, 0.f};

#pragma unroll
  for (int ks = 0; ks < 4; ++ks) {
    int qa = arow * 256 + (ks << 6) + (lk << 4);
    bf16x8 a1h = *reinterpret_cast<const bf16x8*>(ldsb + (qa ^ aswz));
    bf16x8 a1l = *reinterpret_cast<const bf16x8*>(ldsb + 16384 + (qa ^ aswz));
#pragma unroll
    for (int n = 0; n < 8; ++n) {
      int wi = (((n << 4) + lrow) << 4) + (ks << 2) + lk;
      acc[n] = __builtin_amdgcn_mfma_f32_16x16x32_bf16(a1h, Wv1h[wi], acc[n], 0, 0, 0);
      acc[n] = __builtin_amdgcn_mfma_f32_16x16x32_bf16(a1h, Wv1l[wi], acc[n], 0, 0, 0);
      acc[n] = __builtin_amdgcn_mfma_f32_16x16x32_bf16(a1l, Wv1h[wi], acc[n], 0, 0, 0);
    }
    if (MODE >= 1) {
      bf16x8 a2 = *reinterpret_cast<const bf16x8*>(ldsb + 32768 + (qa ^ aswz));
#pragma unroll
      for (int n = 0; n < 8; ++n) {
        int wi = (((n << 4) + lrow) << 4) + (ks << 2) + lk;
        acc[n] = __builtin_amdgcn_mfma_f32_16x16x32_bf16(a2, Wv2h[wi], acc[n], 0, 0, 0);
        acc[n] = __builtin_amdgcn_mfma_f32_16x16x32_bf16(a2, Wv2l[wi], acc[n], 0, 0, 0);
      }
    }
  }

  // epilogue: C/D layout col=lane&15, row=(lane>>4)*4+j
#pragma unroll
  for (int n = 0; n < 8; ++n) {
    int col = (n << 4) + lrow;
    float bv = bias ? bias[col] : 0.f;
    float av = pa ? pa[col] : 1.f;
#pragma unroll
    for (int j = 0; j < 4; ++j) {
      int r = r0 + (wave << 4) + (lk << 2) + j;
      if (r < rows) {
        float x = acc[n][j] + bv;
        if (pa) x = x > 0.f ? x : av * x;
        if (MODE == 2) Cf[(size_t)r * 128 + col] = x;
        else           Cb[(size_t)r * 128 + col] = f2bf(x);
      }
    }
  }
}

// ---------------- mean pool over sorted batch (fp32) ----------------

__device__ __forceinline__ int lower_bound_dev(const int* __restrict__ arr, int n, int val) {
  int lo = 0, hi = n;
  while (lo < hi) {
    int mid = (lo + hi) >> 1;
    if (arr[mid] < val) lo = mid + 1; else hi = mid;
  }
  return lo;
}

__global__ __launch_bounds__(128) void pool_mean(const float* __restrict__ H,
                                                 const int* __restrict__ batch,
                                                 float* __restrict__ pooled) {
  int g = blockIdx.x;
  int t = threadIdx.x;
  int start = lower_bound_dev(batch, NN, g);
  int end = lower_bound_dev(batch, NN, g + 1);
  float acc = 0.f;
  for (int r = start; r < end; ++r) acc += H[(size_t)r * 128 + t];
  int c = end - start;
  float inv = 1.f / (float)(c > 0 ? c : 1);
  pooled[g * 128 + t] = acc * inv;
}

// ---------------- fingerprint head (fp32) ----------------

__global__ __launch_bounds__(128) void fp_head(const float* __restrict__ fp,
                                               const float* __restrict__ Wfp,
                                               const float* __restrict__ bfp,
                                               const float* __restrict__ afp,
                                               float* __restrict__ femb) {
  __shared__ __align__(16) float fs[FPD];
  int g = blockIdx.x;
  int j = threadIdx.x;
  for (int i = j; i < FPD; i += 128) fs[i] = fp[g * FPD + i];
  __syncthreads();
  float acc = bfp[j];
  for (int k = 0; k < FPD; ++k) acc += fs[k] * Wfp[k * 128 + j];
  float a = afp[j];
  femb[g * 128 + j] = acc > 0.f ? acc : a * acc;
}

// ---------------- final ----------------

__global__ __launch_bounds__(64) void final_out(const float* __restrict__ pooled,
                                                const float* __restrict__ femb,
                                                const float* __restrict__ Wp,
                                                const float* __restrict__ bp,
                                                float* __restrict__ out) {
  int g = blockIdx.x;
  int t = threadIdx.x;
  float acc = 0.f;
  for (int i = t; i < 128; i += 64)
    acc += pooled[g * 128 + i] * Wp[i] + femb[g * 128 + i] * Wp[128 + i];
  for (int off = 32; off > 0; off >>= 1) acc += __shfl_down(acc, off);
  if (t == 0) out[g] = acc + bp[0];
}

// ---------------- launch ----------------

extern "C" void kernel_launch(void* const* d_in, const int* in_sizes, int n_in,
                              void* d_out, int out_size, void* d_ws, size_t ws_size,
                              hipStream_t stream) {
  const float* x      = (const float*)d_in[0];
  const float* fp     = (const float*)d_in[1];
  const int*   ei     = (const int*)d_in[2];
  const int*   batch  = (const int*)d_in[3];
  const float* W_pre  = (const float*)d_in[4];
  const float* b_pre  = (const float*)d_in[5];
  const float* a_pre  = (const float*)d_in[6];
  const float* Wl1    = (const float*)d_in[7];
  const float* bl1    = (const float*)d_in[8];
  const float* Wr1    = (const float*)d_in[9];
  const float* a1     = (const float*)d_in[10];
  const float* Wl2    = (const float*)d_in[11];
  const float* bl2    = (const float*)d_in[12];
  const float* Wr2    = (const float*)d_in[13];
  const float* a2     = (const float*)d_in[14];
  const float* W_fp   = (const float*)d_in[15];
  const float* b_fp   = (const float*)d_in[16];
  const float* a_fp   = (const float*)d_in[17];
  const float* W_post = (const float*)d_in[18];
  const float* b_post = (const float*)d_in[19];

  const int* src = ei;
  const int* dst = ei + NE;

  const size_t NBUF = (size_t)NN * 128;  // elements per node-feature buffer
  ushort* buf0 = (ushort*)d_ws;          // x_hi -> agg1_hi -> agg2_hi
  ushort* buf1 = buf0 + NBUF;            // x_lo -> agg1_lo -> agg2_lo
  ushort* buf2 = buf1 + NBUF;            // h0
  ushort* buf3 = buf2 + NBUF;            // h1
  float*  h2f  = (float*)(buf3 + NBUF);  // h2 fp32
  ushort* Wth  = (ushort*)(h2f + NBUF);  // 5*16384
  ushort* Wtl  = Wth + 5 * 16384;        // 5*16384
  int* cnt     = (int*)(Wtl + 5 * 16384);
  int* rowptr  = cnt + NN;               // NN+1 (pad)
  int* bsums   = rowptr + NN + 4;        // 128
  int* cursor  = bsums + 128;            // NN
  int* partial = cursor + NN;            // NN
  int* colsA   = partial + NN;           // NE
  float* pooled = (float*)(colsA + NE);  // NG*128
  float* femb   = pooled + NG * 128;     // NG*128

  // --- CSR build (dst -> srcs) ---
  hipMemsetAsync(cnt, 0, NN * sizeof(int), stream);
  hist_kernel<<<(NE + 255) / 256, 256, 0, stream>>>(dst, cnt, NE);
  int nb = (NN + 1023) / 1024;  // 98
  scan1_kernel<<<nb, 256, 0, stream>>>(cnt, partial, bsums, NN);
  scan2_kernel<<<1, 256, 0, stream>>>(bsums, nb);
  scan3_kernel<<<(NN + 255) / 256, 256, 0, stream>>>(partial, bsums, rowptr, NN);
  hipMemsetAsync(cursor, 0, NN * sizeof(int), stream);
  scatter_kernel<<<(NE + 255) / 256, 256, 0, stream>>>(src, dst, rowptr, cursor, colsA, NE);

  // --- conversions ---
  cvt_x_split<<<(NN * 128 / 4 + 255) / 256, 256, 0, stream>>>(x, buf0, buf1, NN * 128 / 4);
  cvt_w10<<<(5 * 16384 + 255) / 256, 256, 0, stream>>>(W_pre, Wl1, Wr1, Wl2, Wr2, Wth, Wtl);

  const ushort* Wh_pre = Wth;
  const ushort* Wh_l1  = Wth + 16384;
  const ushort* Wh_r1  = Wth + 32768;
  const ushort* Wh_l2  = Wth + 49152;
  const ushort* Wh_r2  = Wth + 65536;
  const ushort* Wl_pre = Wtl;
  const ushort* Wl_l1  = Wtl + 16384;
  const ushort* Wl_r1  = Wtl + 32768;
  const ushort* Wl_l2  = Wtl + 49152;
  const ushort* Wl_r2  = Wtl + 65536;

  int gGemm = (NN + 63) / 64;  // 1563

  // pre_mp: h0 = prelu(x@W_pre + b_pre) -> buf2
  gemm_mfma<0><<<gGemm, 256, 0, stream>>>(buf0, buf1, nullptr, Wh_pre, Wl_pre, nullptr,
                                          nullptr, b_pre, a_pre, buf2, nullptr, NN);

  // conv1: agg(h0) -> buf0/buf1; h1 = prelu(agg@Wl1 + h0@Wr1 + bl1) -> buf3
  agg_bf16<<<NN / 4, 256, 0, stream>>>(buf2, rowptr, colsA, buf0, buf1);
  gemm_mfma<1><<<gGemm, 256, 0, stream>>>(buf0, buf1, buf2, Wh_l1, Wl_l1, Wh_r1, Wl_r1,
                                          bl1, a1, buf3, nullptr, NN);

  // conv2: agg(h1) -> buf0/buf1; h2 = prelu(agg@Wl2 + h1@Wr2 + bl2) -> h2f (fp32)
  agg_bf16<<<NN / 4, 256, 0, stream>>>(buf3, rowptr, colsA, buf0, buf1);
  gemm_mfma<2><<<gGemm, 256, 0, stream>>>(buf0, buf1, buf3, Wh_l2, Wl_l2, Wh_r2, Wl_r2,
                                          bl2, a2, nullptr, h2f, NN);

  // pool + heads
  pool_mean<<<NG, 128, 0, stream>>>(h2f, batch, pooled);
  fp_head<<<NG, 128, 0, stream>>>(fp, W_fp, b_fp, a_fp, femb);
  final_out<<<NG, 64, 0, stream>>>(pooled, femb, W_post, b_post, (float*)d_out);
}

// Round 4
// 713.873 us; speedup vs baseline: 1.3010x; 1.0687x over previous
//
#include <hip/hip_runtime.h>

#define NN 100000
#define NE 1600000
#define NG 512
#define HID 128
#define FPD 2048

typedef __attribute__((ext_vector_type(8))) short bf16x8;
typedef __attribute__((ext_vector_type(4))) float f32x4;

static __device__ __forceinline__ ushort f2bf(float f) {
  union { float f; uint u; } v; v.f = f;
  uint u = v.u;
  uint r = (u + 0x7fffu + ((u >> 16) & 1u)) >> 16;  // RNE
  return (ushort)r;
}
static __device__ __forceinline__ float bf2f(ushort h) {
  union { uint u; float f; } v; v.u = ((uint)h) << 16;
  return v.f;
}

// ---------------- CSR build ----------------

__global__ __launch_bounds__(256) void hist_kernel(const int* __restrict__ dst,
                                                   int* __restrict__ cnt, int E) {
  int i = blockIdx.x * 256 + threadIdx.x;
  if (i < E) atomicAdd(&cnt[dst[i]], 1);
}

__global__ __launch_bounds__(256) void scan1_kernel(const int* __restrict__ cnt,
                                                    int* __restrict__ partial,
                                                    int* __restrict__ bsums, int n) {
  __shared__ int lds[256];
  int t = threadIdx.x;
  int base = blockIdx.x * 1024 + t * 4;
  int4 v = make_int4(0, 0, 0, 0);
  if (base + 3 < n) {
    v = *reinterpret_cast<const int4*>(&cnt[base]);
  } else {
    if (base     < n) v.x = cnt[base];
    if (base + 1 < n) v.y = cnt[base + 1];
    if (base + 2 < n) v.z = cnt[base + 2];
    if (base + 3 < n) v.w = cnt[base + 3];
  }
  int s = v.x + v.y + v.z + v.w;
  lds[t] = s;
  __syncthreads();
  for (int off = 1; off < 256; off <<= 1) {
    int add = (t >= off) ? lds[t - off] : 0;
    __syncthreads();
    lds[t] += add;
    __syncthreads();
  }
  int run = lds[t] - s;
  run += v.x; if (base     < n) partial[base]     = run;
  run += v.y; if (base + 1 < n) partial[base + 1] = run;
  run += v.z; if (base + 2 < n) partial[base + 2] = run;
  run += v.w; if (base + 3 < n) partial[base + 3] = run;
  if (t == 255) bsums[blockIdx.x] = lds[255];
}

__global__ __launch_bounds__(256) void scan2_kernel(int* __restrict__ bsums, int nb) {
  __shared__ int lds[256];
  int t = threadIdx.x;
  int s = (t < nb) ? bsums[t] : 0;
  lds[t] = s;
  __syncthreads();
  for (int off = 1; off < 256; off <<= 1) {
    int add = (t >= off) ? lds[t - off] : 0;
    __syncthreads();
    lds[t] += add;
    __syncthreads();
  }
  if (t < nb) bsums[t] = lds[t] - s;
}

__global__ __launch_bounds__(256) void scan3_kernel(const int* __restrict__ partial,
                                                    const int* __restrict__ bsums,
                                                    int* __restrict__ rowptr, int n) {
  int i = blockIdx.x * 256 + threadIdx.x;
  if (i == 0) rowptr[0] = 0;
  if (i < n) rowptr[i + 1] = partial[i] + bsums[i >> 10];
}

__global__ __launch_bounds__(256) void scatter_kernel(const int* __restrict__ src,
                                                      const int* __restrict__ dst,
                                                      const int* __restrict__ rowptr,
                                                      int* __restrict__ cursor,
                                                      int* __restrict__ cols, int E) {
  int i = blockIdx.x * 256 + threadIdx.x;
  if (i < E) {
    int d = dst[i];
    int p = atomicAdd(&cursor[d], 1);
    cols[rowptr[d] + p] = src[i];
  }
}

// ---------------- conversions ----------------

__global__ __launch_bounds__(256) void cvt_x_split(const float* __restrict__ x,
                                                   ushort* __restrict__ xh,
                                                   ushort* __restrict__ xl, int n4) {
  int i = blockIdx.x * 256 + threadIdx.x;
  if (i < n4) {
    float4 v = *reinterpret_cast<const float4*>(&x[i * 4]);
    ushort4 h, l;
    h.x = f2bf(v.x); l.x = f2bf(v.x - bf2f(h.x));
    h.y = f2bf(v.y); l.y = f2bf(v.y - bf2f(h.y));
    h.z = f2bf(v.z); l.z = f2bf(v.z - bf2f(h.z));
    h.w = f2bf(v.w); l.w = f2bf(v.w - bf2f(h.w));
    *reinterpret_cast<ushort4*>(&xh[i * 4]) = h;
    *reinterpret_cast<ushort4*>(&xl[i * 4]) = l;
  }
}

// transpose + hi/lo split 5 [128][128] weights: Wt[w][j][k] = W[k][j]
__global__ __launch_bounds__(256) void cvt_w10(const float* __restrict__ w0,
                                               const float* __restrict__ w1,
                                               const float* __restrict__ w2,
                                               const float* __restrict__ w3,
                                               const float* __restrict__ w4,
                                               ushort* __restrict__ outh,
                                               ushort* __restrict__ outl) {
  int idx = blockIdx.x * 256 + threadIdx.x;  // 5*16384
  if (idx >= 5 * 16384) return;
  int w = idx >> 14, rem = idx & 16383;
  int j = rem >> 7, k = rem & 127;
  const float* W = (w == 0) ? w0 : (w == 1) ? w1 : (w == 2) ? w2 : (w == 3) ? w3 : w4;
  float v = W[k * 128 + j];
  ushort h = f2bf(v);
  outh[idx] = h;
  outl[idx] = f2bf(v - bf2f(h));
}

// ---------------- aggregation (bf16 in, hi/lo bf16 out) ----------------

__global__ __launch_bounds__(256) void agg_bf16(const ushort* __restrict__ H,
                                                const int* __restrict__ rowptr,
                                                const int* __restrict__ cols,
                                                ushort* __restrict__ outh,
                                                ushort* __restrict__ outl) {
  int node = blockIdx.x * 4 + (threadIdx.x >> 6);
  int lane = threadIdx.x & 63;
  int s = rowptr[node], e = rowptr[node + 1];
  float a0 = 0.f, a1 = 0.f;
  int i = s;
  for (; i + 3 < e; i += 4) {
    int c0 = cols[i], c1 = cols[i + 1], c2 = cols[i + 2], c3 = cols[i + 3];
    uint u0 = *reinterpret_cast<const uint*>(&H[(size_t)c0 * 128 + lane * 2]);
    uint u1 = *reinterpret_cast<const uint*>(&H[(size_t)c1 * 128 + lane * 2]);
    uint u2 = *reinterpret_cast<const uint*>(&H[(size_t)c2 * 128 + lane * 2]);
    uint u3 = *reinterpret_cast<const uint*>(&H[(size_t)c3 * 128 + lane * 2]);
    a0 += bf2f((ushort)(u0 & 0xffff)) + bf2f((ushort)(u1 & 0xffff)) +
          bf2f((ushort)(u2 & 0xffff)) + bf2f((ushort)(u3 & 0xffff));
    a1 += bf2f((ushort)(u0 >> 16)) + bf2f((ushort)(u1 >> 16)) +
          bf2f((ushort)(u2 >> 16)) + bf2f((ushort)(u3 >> 16));
  }
  for (; i < e; ++i) {
    uint u0 = *reinterpret_cast<const uint*>(&H[(size_t)cols[i] * 128 + lane * 2]);
    a0 += bf2f((ushort)(u0 & 0xffff));
    a1 += bf2f((ushort)(u0 >> 16));
  }
  ushort h0 = f2bf(a0), h1 = f2bf(a1);
  ushort l0 = f2bf(a0 - bf2f(h0)), l1 = f2bf(a1 - bf2f(h1));
  *reinterpret_cast<uint*>(&outh[(size_t)node * 128 + lane * 2]) = (uint)h0 | ((uint)h1 << 16);
  *reinterpret_cast<uint*>(&outl[(size_t)node * 128 + lane * 2]) = (uint)l0 | ((uint)l1 << 16);
}

// ---------------- MFMA GEMM, no LDS, direct-register fragments ----------------
// MODE 0: C = prelu(A1@W1 + bias)          terms: A1h@W1h + A1h@W1l + A1l@W1h
// MODE 1: C = prelu(A1@W1 + A2@W2 + bias)  terms: + A2@W2h + A2@W2l   (bf16 out)
// MODE 2: same as 1, fp32 out
// 1 wave per block; wave computes 32 rows x 128 cols (2 row-groups, acc[2][8]).
// A frag: lane(lrow=l&15, lk=l>>4) reads A[row][ks*32 + lk*8], 16B.
// W frag: Wt[j][k] row-major; chunk index ((n*16+lrow)<<4) + ks*4 + lk.

template <int MODE>
__global__ __launch_bounds__(64) void gemm_mfma(const ushort* __restrict__ A1h,
                                                const ushort* __restrict__ A1l,
                                                const ushort* __restrict__ A2,
                                                const ushort* __restrict__ W1h,
                                                const ushort* __restrict__ W1l,
                                                const ushort* __restrict__ W2h,
                                                const ushort* __restrict__ W2l,
                                                const float* __restrict__ bias,
                                                const float* __restrict__ pa,
                                                ushort* __restrict__ Cb,
                                                float* __restrict__ Cf, int rows) {
  int lane = threadIdx.x;
  int lrow = lane & 15, lk = lane >> 4;
  int r0 = blockIdx.x * 32;

  const bf16x8* Wv1h = reinterpret_cast<const bf16x8*>(W1h);
  const bf16x8* Wv1l = reinterpret_cast<const bf16x8*>(W1l);
  const bf16x8* Wv2h = reinterpret_cast<const bf16x8*>(W2h);
  const bf16x8* Wv2l = reinterpret_cast<const bf16x8*>(W2l);

  f32x4 acc[2][8];
#pragma unroll
  for (int g = 0; g < 2; ++g)
#pragma unroll
    for (int n = 0; n < 8; ++n) acc[g][n] = (f32x4){0.f, 0.f, 0.f, 0.f};

#pragma unroll
  for (int ks = 0; ks < 4; ++ks) {
    bf16x8 a1h[2], a1l[2], a2[2];
#pragma unroll
    for (int g = 0; g < 2; ++g) {
      int r = r0 + g * 16 + lrow;
      if (r > rows - 1) r = rows - 1;
      size_t off = (size_t)r * 128 + (ks << 5) + (lk << 3);
      a1h[g] = *reinterpret_cast<const bf16x8*>(&A1h[off]);
      a1l[g] = *reinterpret_cast<const bf16x8*>(&A1l[off]);
      if (MODE >= 1) a2[g] = *reinterpret_cast<const bf16x8*>(&A2[off]);
    }
#pragma unroll
    for (int n = 0; n < 8; ++n) {
      int wi = (((n << 4) + lrow) << 4) + (ks << 2) + lk;
      bf16x8 b1h = Wv1h[wi];
      bf16x8 b1l = Wv1l[wi];
#pragma unroll
      for (int g = 0; g < 2; ++g) {
        acc[g][n] = __builtin_amdgcn_mfma_f32_16x16x32_bf16(a1h[g], b1h, acc[g][n], 0, 0, 0);
        acc[g][n] = __builtin_amdgcn_mfma_f32_16x16x32_bf16(a1h[g], b1l, acc[g][n], 0, 0, 0);
        acc[g][n] = __builtin_amdgcn_mfma_f32_16x16x32_bf16(a1l[g], b1h, acc[g][n], 0, 0, 0);
      }
      if (MODE >= 1) {
        bf16x8 b2h = Wv2h[wi];
        bf16x8 b2l = Wv2l[wi];
#pragma unroll
        for (int g = 0; g < 2; ++g) {
          acc[g][n] = __builtin_amdgcn_mfma_f32_16x16x32_bf16(a2[g], b2h, acc[g][n], 0, 0, 0);
          acc[g][n] = __builtin_amdgcn_mfma_f32_16x16x32_bf16(a2[g], b2l, acc[g][n], 0, 0, 0);
        }
      }
    }
  }

  // epilogue: C/D layout col=lane&15, row_in_tile=(lane>>4)*4+j
#pragma unroll
  for (int n = 0; n < 8; ++n) {
    int col = (n << 4) + lrow;
    float bv = bias ? bias[col] : 0.f;
    float av = pa ? pa[col] : 1.f;
#pragma unroll
    for (int g = 0; g < 2; ++g) {
#pragma unroll
      for (int j = 0; j < 4; ++j) {
        int r = r0 + g * 16 + (lk << 2) + j;
        if (r < rows) {
          float x = acc[g][n][j] + bv;
          if (pa) x = x > 0.f ? x : av * x;
          if (MODE == 2) Cf[(size_t)r * 128 + col] = x;
          else           Cb[(size_t)r * 128 + col] = f2bf(x);
        }
      }
    }
  }
}

// ---------------- mean pool over sorted batch (fp32) ----------------

__device__ __forceinline__ int lower_bound_dev(const int* __restrict__ arr, int n, int val) {
  int lo = 0, hi = n;
  while (lo < hi) {
    int mid = (lo + hi) >> 1;
    if (arr[mid] < val) lo = mid + 1; else hi = mid;
  }
  return lo;
}

__global__ __launch_bounds__(128) void pool_mean(const float* __restrict__ H,
                                                 const int* __restrict__ batch,
                                                 float* __restrict__ pooled) {
  int g = blockIdx.x;
  int t = threadIdx.x;
  int start = lower_bound_dev(batch, NN, g);
  int end = lower_bound_dev(batch, NN, g + 1);
  float acc = 0.f;
  for (int r = start; r < end; ++r) acc += H[(size_t)r * 128 + t];
  int c = end - start;
  float inv = 1.f / (float)(c > 0 ? c : 1);
  pooled[g * 128 + t] = acc * inv;
}

// ---------------- fingerprint head (fp32) ----------------

__global__ __launch_bounds__(128) void fp_head(const float* __restrict__ fp,
                                               const float* __restrict__ Wfp,
                                               const float* __restrict__ bfp,
                                               const float* __restrict__ afp,
                                               float* __restrict__ femb) {
  __shared__ __align__(16) float fs[FPD];
  int g = blockIdx.x;
  int j = threadIdx.x;
  for (int i = j; i < FPD; i += 128) fs[i] = fp[g * FPD + i];
  __syncthreads();
  float acc = bfp[j];
  for (int k = 0; k < FPD; ++k) acc += fs[k] * Wfp[k * 128 + j];
  float a = afp[j];
  femb[g * 128 + j] = acc > 0.f ? acc : a * acc;
}

// ---------------- final ----------------

__global__ __launch_bounds__(64) void final_out(const float* __restrict__ pooled,
                                                const float* __restrict__ femb,
                                                const float* __restrict__ Wp,
                                                const float* __restrict__ bp,
                                                float* __restrict__ out) {
  int g = blockIdx.x;
  int t = threadIdx.x;
  float acc = 0.f;
  for (int i = t; i < 128; i += 64)
    acc += pooled[g * 128 + i] * Wp[i] + femb[g * 128 + i] * Wp[128 + i];
  for (int off = 32; off > 0; off >>= 1) acc += __shfl_down(acc, off);
  if (t == 0) out[g] = acc + bp[0];
}

// ---------------- launch ----------------

extern "C" void kernel_launch(void* const* d_in, const int* in_sizes, int n_in,
                              void* d_out, int out_size, void* d_ws, size_t ws_size,
                              hipStream_t stream) {
  const float* x      = (const float*)d_in[0];
  const float* fp     = (const float*)d_in[1];
  const int*   ei     = (const int*)d_in[2];
  const int*   batch  = (const int*)d_in[3];
  const float* W_pre  = (const float*)d_in[4];
  const float* b_pre  = (const float*)d_in[5];
  const float* a_pre  = (const float*)d_in[6];
  const float* Wl1    = (const float*)d_in[7];
  const float* bl1    = (const float*)d_in[8];
  const float* Wr1    = (const float*)d_in[9];
  const float* a1     = (const float*)d_in[10];
  const float* Wl2    = (const float*)d_in[11];
  const float* bl2    = (const float*)d_in[12];
  const float* Wr2    = (const float*)d_in[13];
  const float* a2     = (const float*)d_in[14];
  const float* W_fp   = (const float*)d_in[15];
  const float* b_fp   = (const float*)d_in[16];
  const float* a_fp   = (const float*)d_in[17];
  const float* W_post = (const float*)d_in[18];
  const float* b_post = (const float*)d_in[19];

  const int* src = ei;
  const int* dst = ei + NE;

  const size_t NBUF = (size_t)NN * 128;
  ushort* buf0 = (ushort*)d_ws;          // x_hi -> agg_hi
  ushort* buf1 = buf0 + NBUF;            // x_lo -> agg_lo
  ushort* buf2 = buf1 + NBUF;            // h0
  ushort* buf3 = buf2 + NBUF;            // h1
  float*  h2f  = (float*)(buf3 + NBUF);  // h2 fp32
  ushort* Wth  = (ushort*)(h2f + NBUF);
  ushort* Wtl  = Wth + 5 * 16384;
  int* cnt     = (int*)(Wtl + 5 * 16384);
  int* rowptr  = cnt + NN;
  int* bsums   = rowptr + NN + 4;
  int* cursor  = bsums + 128;
  int* partial = cursor + NN;
  int* colsA   = partial + NN;
  float* pooled = (float*)(colsA + NE);
  float* femb   = pooled + NG * 128;

  // --- CSR build (dst -> srcs) ---
  hipMemsetAsync(cnt, 0, NN * sizeof(int), stream);
  hist_kernel<<<(NE + 255) / 256, 256, 0, stream>>>(dst, cnt, NE);
  int nb = (NN + 1023) / 1024;  // 98
  scan1_kernel<<<nb, 256, 0, stream>>>(cnt, partial, bsums, NN);
  scan2_kernel<<<1, 256, 0, stream>>>(bsums, nb);
  scan3_kernel<<<(NN + 255) / 256, 256, 0, stream>>>(partial, bsums, rowptr, NN);
  hipMemsetAsync(cursor, 0, NN * sizeof(int), stream);
  scatter_kernel<<<(NE + 255) / 256, 256, 0, stream>>>(src, dst, rowptr, cursor, colsA, NE);

  // --- conversions ---
  cvt_x_split<<<(NN * 128 / 4 + 255) / 256, 256, 0, stream>>>(x, buf0, buf1, NN * 128 / 4);
  cvt_w10<<<(5 * 16384 + 255) / 256, 256, 0, stream>>>(W_pre, Wl1, Wr1, Wl2, Wr2, Wth, Wtl);

  const ushort* Wh_pre = Wth;
  const ushort* Wh_l1  = Wth + 16384;
  const ushort* Wh_r1  = Wth + 32768;
  const ushort* Wh_l2  = Wth + 49152;
  const ushort* Wh_r2  = Wth + 65536;
  const ushort* Wl_pre = Wtl;
  const ushort* Wl_l1  = Wtl + 16384;
  const ushort* Wl_r1  = Wtl + 32768;
  const ushort* Wl_l2  = Wtl + 49152;
  const ushort* Wl_r2  = Wtl + 65536;

  int gGemm = (NN + 31) / 32;  // 3125, 1 wave each

  // pre_mp: h0 = prelu(x@W_pre + b_pre) -> buf2
  gemm_mfma<0><<<gGemm, 64, 0, stream>>>(buf0, buf1, nullptr, Wh_pre, Wl_pre, nullptr,
                                         nullptr, b_pre, a_pre, buf2, nullptr, NN);

  // conv1: agg(h0) -> buf0/buf1; h1 = prelu(agg@Wl1 + h0@Wr1 + bl1) -> buf3
  agg_bf16<<<NN / 4, 256, 0, stream>>>(buf2, rowptr, colsA, buf0, buf1);
  gemm_mfma<1><<<gGemm, 64, 0, stream>>>(buf0, buf1, buf2, Wh_l1, Wl_l1, Wh_r1, Wl_r1,
                                         bl1, a1, buf3, nullptr, NN);

  // conv2: agg(h1) -> buf0/buf1; h2 = prelu(agg@Wl2 + h1@Wr2 + bl2) -> h2f (fp32)
  agg_bf16<<<NN / 4, 256, 0, stream>>>(buf3, rowptr, colsA, buf0, buf1);
  gemm_mfma<2><<<gGemm, 64, 0, stream>>>(buf0, buf1, buf3, Wh_l2, Wl_l2, Wh_r2, Wl_r2,
                                         bl2, a2, nullptr, h2f, NN);

  // pool + heads
  pool_mean<<<NG, 128, 0, stream>>>(h2f, batch, pooled);
  fp_head<<<NG, 128, 0, stream>>>(fp, W_fp, b_fp, a_fp, femb);
  final_out<<<NG, 64, 0, stream>>>(pooled, femb, W_post, b_post, (float*)d_out);
}